// Round 8
// baseline (581.400 us; speedup 1.0000x reference)
//
#include <hip/hip_runtime.h>
#include <hip/hip_bf16.h>
#include <math.h>

#define Bn 4
#define Sn 1024
#define Dn 512
#define NHn 8
#define HDn 64
#define KNn 16384
#define KLn 8
#define NCn 4
#define Mn (Bn*Sn)   // 4096 rows

typedef __attribute__((ext_vector_type(8))) short short8;
typedef __attribute__((ext_vector_type(4))) float f32x4;
typedef unsigned long long u64;

#define MFMA16(a,b,c) __builtin_amdgcn_mfma_f32_16x16x32_bf16(a,b,c,0,0,0)

// ---------------- helpers ----------------

__device__ __forceinline__ float wred_sum(float v){
  #pragma unroll
  for (int m=1;m<64;m<<=1) v += __shfl_xor(v, m, 64);
  return v;
}

__device__ __forceinline__ ushort f2bf(float f){
  __hip_bfloat16 h = __float2bfloat16(f);
  return __builtin_bit_cast(ushort, h);
}
__device__ __forceinline__ float bf2f(ushort u){
  return __builtin_bit_cast(float, ((unsigned)u)<<16);
}

// sortable key: value asc <-> key asc; tie -> smaller index = larger key.
__device__ __forceinline__ unsigned int fkey(float v){
  unsigned int b = __builtin_bit_cast(unsigned int, v);
  return (b & 0x80000000u) ? ~b : (b | 0x80000000u);
}
__device__ __forceinline__ u64 mkkey(float v, int idx){
  return ((u64)fkey(v) << 32) | (u64)(0xFFFFu - (unsigned)idx);
}

__device__ __forceinline__ void cex64(u64& a, u64& b){
  u64 mx = a > b ? a : b;
  u64 mn = a > b ? b : a;
  a = mx; b = mn;
}
__device__ __forceinline__ void ins4_64(u64 k, u64&k0,u64&k1,u64&k2,u64&k3){
  if (k > k3){
    k3 = k;
    cex64(k2,k3); cex64(k1,k2); cex64(k0,k1);
  }
}
__device__ __forceinline__ void merge4_64(u64&a0,u64&a1,u64&a2,u64&a3,
                                          u64 b0,u64 b1,u64 b2,u64 b3){
  cex64(a0,b3); cex64(a1,b2); cex64(a2,b1); cex64(a3,b0);
  cex64(a0,a2); cex64(a1,a3);
  cex64(a0,a1); cex64(a2,a3);
}

// ---------------- 1. RMSNorm(x) -> hn (bf16) ----------------

__global__ __launch_bounds__(256) void rmsnorm_kernel(const float* __restrict__ x,
                                                      const float* __restrict__ w,
                                                      ushort* __restrict__ y){
  int row = blockIdx.x, tid = threadIdx.x;
  const float2* xr = (const float2*)(x + (size_t)row*Dn);
  float2 v = xr[tid];
  float ss = v.x*v.x + v.y*v.y;
  ss = wred_sum(ss);
  __shared__ float red[4];
  int wid = tid>>6, lane = tid&63;
  if (lane==0) red[wid]=ss;
  __syncthreads();
  float tot = red[0]+red[1]+red[2]+red[3];
  float sc = rsqrtf(tot*(1.0f/Dn) + 1e-5f);
  float2 wv = ((const float2*)w)[tid];
  ushort2 u; u.x = f2bf(v.x*sc*wv.x); u.y = f2bf(v.y*sc*wv.y);
  *(ushort2*)&y[(size_t)row*Dn + tid*2] = u;
}

// ------- transpose-convert: src f32 (K x N) -> dst bf16 (N x K) -------

__device__ __forceinline__ void convT_body(const float* __restrict__ src,
                                           ushort* __restrict__ dst,
                                           int ldsrc, int lddst,
                                           int n0, int k0, int tid){
  __shared__ float T[64][68];
  #pragma unroll
  for (int h=0;h<4;h++){
    int idx = tid + h*256;
    int r = idx>>4, c = (idx&15)*4;
    float4 v = *(const float4*)&src[(size_t)(k0+r)*ldsrc + n0+c];
    *(float4*)&T[r][c] = v;
  }
  __syncthreads();
  #pragma unroll
  for (int h=0;h<4;h++){
    int idx = tid + h*256;
    int n = idx>>4, kc = (idx&15)*4;
    ushort4 u;
    u.x = f2bf(T[kc+0][n]);
    u.y = f2bf(T[kc+1][n]);
    u.z = f2bf(T[kc+2][n]);
    u.w = f2bf(T[kc+3][n]);
    *(ushort4*)&dst[(size_t)(n0+n)*lddst + k0+kc] = u;
  }
}

__global__ __launch_bounds__(256) void convT_kernel(const float* __restrict__ src,
                                                    ushort* __restrict__ dst,
                                                    int ldsrc, int lddst){
  convT_body(src, dst, ldsrc, lddst, blockIdx.x*64, blockIdx.y*64, threadIdx.x);
}

// 4 x (512x512) -> contiguous dst (z-selected)
__global__ __launch_bounds__(256) void convT4_kernel(const float* __restrict__ s0,
                                                     const float* __restrict__ s1,
                                                     const float* __restrict__ s2,
                                                     const float* __restrict__ s3,
                                                     ushort* __restrict__ dst){
  const float* src = (blockIdx.z==0)?s0 : (blockIdx.z==1)?s1 : (blockIdx.z==2)?s2 : s3;
  convT_body(src, dst + (size_t)blockIdx.z*(512*512), 512, 512,
             blockIdx.x*64, blockIdx.y*64, threadIdx.x);
}

// 2 x (1024x512) -> contiguous dst (z-selected)
__global__ __launch_bounds__(256) void convT2_kernel(const float* __restrict__ s0,
                                                     const float* __restrict__ s1,
                                                     ushort* __restrict__ dst){
  const float* src = (blockIdx.z==0)?s0 : s1;
  convT_body(src, dst + (size_t)blockIdx.z*(512*1024), 512, 1024,
             blockIdx.x*64, blockIdx.y*64, threadIdx.x);
}

// ---------------- generic bf16 MFMA GEMM, 64x64 tile, BK=64 ----------------
// MODE 0: f32 C[mm*ldc+n] = val
// MODE 3: bf16 out, plain row-major
// MODE 4: QKV fused: BT = [wq|wk|wv]^T (1536x512); which=n>>9 -> q/k/v buffers
//         (B*NH,S,HD) relayout; RoPE for which<2.

template<int MODE>
__global__ __launch_bounds__(256) void gemm_bf16(const ushort* __restrict__ A, int lda,
                                                 const ushort* __restrict__ BT, int K,
                                                 void* __restrict__ Cv, int ldc,
                                                 const float* __restrict__ pc,
                                                 const float* __restrict__ ps){
  __shared__ __align__(16) ushort As[64*72];
  __shared__ __align__(16) ushort Bs[64*72];
  int tid=threadIdx.x;
  int w = tid>>6, l = tid&63;
  int wr = w>>1, wc = w&1;
  int g = l>>4, li = l&15;
  int m0 = blockIdx.y*64, n0 = blockIdx.x*64;
  f32x4 acc[2][2] = {};
  for (int kt=0; kt<K; kt+=64){
    #pragma unroll
    for (int t=0;t<2;t++){
      int ch = tid + t*256;
      int r = ch>>3, c = (ch&7)*8;
      *(uint4*)&As[r*72+c] = *(const uint4*)&A [(size_t)(m0+r)*lda + kt + c];
      *(uint4*)&Bs[r*72+c] = *(const uint4*)&BT[(size_t)(n0+r)*K   + kt + c];
    }
    __syncthreads();
    #pragma unroll
    for (int kk=0;kk<2;kk++){
      short8 a0 = *(const short8*)&As[(wr*32 +      li)*72 + kk*32 + g*8];
      short8 a1 = *(const short8*)&As[(wr*32 + 16 + li)*72 + kk*32 + g*8];
      short8 b0 = *(const short8*)&Bs[(wc*32 +      li)*72 + kk*32 + g*8];
      short8 b1 = *(const short8*)&Bs[(wc*32 + 16 + li)*72 + kk*32 + g*8];
      acc[0][0] = MFMA16(a0, b0, acc[0][0]);
      acc[0][1] = MFMA16(a0, b1, acc[0][1]);
      acc[1][0] = MFMA16(a1, b0, acc[1][0]);
      acc[1][1] = MFMA16(a1, b1, acc[1][1]);
    }
    __syncthreads();
  }
  #pragma unroll
  for (int mi=0;mi<2;mi++){
    #pragma unroll
    for (int ni=0;ni<2;ni++){
      #pragma unroll
      for (int reg=0;reg<4;reg++){
        int mm = m0 + wr*32 + mi*16 + g*4 + reg;
        int n  = n0 + wc*32 + ni*16 + li;
        float val = acc[mi][ni][reg];
        if (MODE==0){
          ((float*)Cv)[(size_t)mm*ldc + n] = val;
        } else if (MODE==3){
          ((ushort*)Cv)[(size_t)mm*ldc + n] = f2bf(val);
        } else {
          int which = n>>9, nn = n&511;
          int b = mm>>10, s2 = mm&1023, h = nn>>6, d = nn&63;
          size_t o = (size_t)which*((size_t)Mn*Dn)
                   + ((size_t)(b*NHn + h)*Sn + s2)*HDn + d;
          if (which==2){
            ((ushort*)Cv)[o] = f2bf(val);
          } else {
            float other = __shfl_xor(val, 1, 64);
            float cc = pc[s2*32 + (d>>1)], snv = ps[s2*32 + (d>>1)];
            float rv = ((li&1)==0) ? val*cc - other*snv : other*snv + val*cc;
            ((ushort*)Cv)[o] = f2bf(rv);
          }
        }
      }
    }
  }
}

// ---------------- 3. bf16 MFMA causal flash attention (unchanged) ----------------

__global__ __launch_bounds__(256) void attn_mfma(const ushort* __restrict__ q,
                                                 const ushort* __restrict__ k,
                                                 const ushort* __restrict__ v,
                                                 ushort* __restrict__ o){
  __shared__ __align__(16) ushort Ks[64*72];
  __shared__ __align__(16) ushort VTs[64*64];
  __shared__ __align__(16) ushort Ps[4][16*72];
  int tid = threadIdx.x;
  int w = tid>>6, l = tid&63;
  int g = l>>4, li = l&15;
  int qt = blockIdx.x, bh = blockIdx.y;
  const ushort* Qg = q + ((size_t)bh*Sn + qt*64 + w*16)*HDn;
  const ushort* Kg = k + (size_t)bh*Sn*HDn;
  const ushort* Vg = v + (size_t)bh*Sn*HDn;
  short8 aq0 = *(const short8*)&Qg[(size_t)li*HDn + g*8];
  short8 aq1 = *(const short8*)&Qg[(size_t)li*HDn + 32 + g*8];
  f32x4 oacc[4] = {};
  float mreg[4] = {-1e30f,-1e30f,-1e30f,-1e30f};
  float lreg[4] = {0.f,0.f,0.f,0.f};
  for (int kt=0; kt<=qt; kt++){
    #pragma unroll
    for (int t=0;t<2;t++){
      int ch = tid + t*256;
      int r = ch>>3, c = (ch&7)*8;
      short8 kv8 = *(const short8*)&Kg[(size_t)(kt*64+r)*HDn + c];
      short8 vv8 = *(const short8*)&Vg[(size_t)(kt*64+r)*HDn + c];
      *(short8*)&Ks[r*72 + c] = kv8;
      #pragma unroll
      for (int j=0;j<8;j++){
        int d = c+j;
        int byteoff = d*128 + ((((r>>3) ^ (d>>3)) & 7)<<4) + (r&7)*2;
        *(ushort*)((char*)VTs + byteoff) = (ushort)vv8[j];
      }
    }
    __syncthreads();
    f32x4 s[4] = {};
    #pragma unroll
    for (int n=0;n<4;n++){
      short8 b0 = *(const short8*)&Ks[(n*16+li)*72 + g*8];
      short8 b1 = *(const short8*)&Ks[(n*16+li)*72 + 32 + g*8];
      s[n] = MFMA16(aq0, b0, s[n]);
      s[n] = MFMA16(aq1, b1, s[n]);
    }
    if (kt == qt){
      #pragma unroll
      for (int n=0;n<4;n++){
        int kvg = n*16 + li;
        #pragma unroll
        for (int reg=0;reg<4;reg++){
          int qg = w*16 + g*4 + reg;
          s[n][reg] = (kvg <= qg) ? s[n][reg]*0.125f : -1e9f;
        }
      }
    } else {
      #pragma unroll
      for (int n=0;n<4;n++)
        #pragma unroll
        for (int reg=0;reg<4;reg++) s[n][reg] *= 0.125f;
    }
    #pragma unroll
    for (int reg=0;reg<4;reg++){
      float mt = fmaxf(fmaxf(s[0][reg],s[1][reg]), fmaxf(s[2][reg],s[3][reg]));
      mt = fmaxf(mt, __shfl_xor(mt,1,64));
      mt = fmaxf(mt, __shfl_xor(mt,2,64));
      mt = fmaxf(mt, __shfl_xor(mt,4,64));
      mt = fmaxf(mt, __shfl_xor(mt,8,64));
      float mn = fmaxf(mreg[reg], mt);
      float sc = __expf(mreg[reg]-mn);
      mreg[reg] = mn;
      float p0 = __expf(s[0][reg]-mn), p1 = __expf(s[1][reg]-mn);
      float p2 = __expf(s[2][reg]-mn), p3 = __expf(s[3][reg]-mn);
      s[0][reg]=p0; s[1][reg]=p1; s[2][reg]=p2; s[3][reg]=p3;
      float sm = p0+p1+p2+p3;
      sm += __shfl_xor(sm,1,64);
      sm += __shfl_xor(sm,2,64);
      sm += __shfl_xor(sm,4,64);
      sm += __shfl_xor(sm,8,64);
      lreg[reg] = lreg[reg]*sc + sm;
      #pragma unroll
      for (int n=0;n<4;n++) oacc[n][reg] *= sc;
    }
    #pragma unroll
    for (int n=0;n<4;n++)
      #pragma unroll
      for (int reg=0;reg<4;reg++)
        Ps[w][(g*4+reg)*72 + n*16 + li] = f2bf(s[n][reg]);
    #pragma unroll
    for (int kk=0;kk<2;kk++){
      short8 ap = *(const short8*)&Ps[w][li*72 + kk*32 + g*8];
      #pragma unroll
      for (int n=0;n<4;n++){
        int d = n*16 + li;
        int gran = ((kk*4 + g) ^ (d>>3)) & 7;
        short8 bv = *(const short8*)((char*)VTs + d*128 + (gran<<4));
        oacc[n] = MFMA16(ap, bv, oacc[n]);
      }
    }
    __syncthreads();
  }
  int b = bh>>3, h = bh&7;
  #pragma unroll
  for (int reg=0;reg<4;reg++){
    int qg = qt*64 + w*16 + g*4 + reg;
    float inv = 1.f/lreg[reg];
    #pragma unroll
    for (int n=0;n<4;n++)
      o[((size_t)(b*Sn+qg))*Dn + h*HDn + n*16 + li] = f2bf(oacc[n][reg]*inv);
  }
}

// --- 5. h = x + h_attn(bf16) ; hm = rms(h_attn)*w -> hm32 (f32) + cat_bf[:, :512] ---

__global__ __launch_bounds__(256) void h_hm_kernel(const float* __restrict__ x,
                                                   const ushort* __restrict__ ha,
                                                   const float* __restrict__ w,
                                                   float* __restrict__ h,
                                                   float* __restrict__ hm32,
                                                   ushort* __restrict__ cat_bf){
  int row=blockIdx.x, tid=threadIdx.x;
  ushort2 a2 = *(const ushort2*)&ha[(size_t)row*Dn + tid*2];
  float ax = bf2f(a2.x), ay = bf2f(a2.y);
  float2 xv = ((const float2*)(x + (size_t)row*Dn))[tid];
  float ss = ax*ax + ay*ay;
  ss = wred_sum(ss);
  __shared__ float red[4];
  int wid=tid>>6, lane=tid&63;
  if (lane==0) red[wid]=ss;
  __syncthreads();
  float tot = red[0]+red[1]+red[2]+red[3];
  float sc = rsqrtf(tot*(1.0f/Dn) + 1e-5f);
  float2 wv = ((const float2*)w)[tid];
  float hm0 = ax*sc*wv.x, hm1 = ay*sc*wv.y;
  ((float2*)(h + (size_t)row*Dn))[tid] = make_float2(xv.x+ax, xv.y+ay);
  ((float2*)(hm32 + (size_t)row*Dn))[tid] = make_float2(hm0, hm1);
  ushort2 u; u.x = f2bf(hm0); u.y = f2bf(hm1);
  *(ushort2*)&cat_bf[(size_t)row*1024 + tid*2] = u;
}

// ---------------- 6. logits GEMM with SWAPPED operands + 16-col group-max ----------------
// acc[i][n] = mfma(b[n], a[i]): lane(g,li) holds logit[row = m0+wr*64+i*16+li]
//                                               [col = n0+wc*64+n*16+g*4+reg]
// Group max (16 cols) = 3 in-lane fmax + 2 shfl_xor over g. gmaxT[1024][4096].

__global__ __launch_bounds__(256) void logits_gmax(const ushort* __restrict__ Abf,
                                                   const ushort* __restrict__ BT,
                                                   float* __restrict__ gmaxT){
  __shared__ __align__(16) ushort As[128*40];
  __shared__ __align__(16) ushort Bs[128*40];
  int tid=threadIdx.x;
  int w = tid>>6, l = tid&63;
  int wr = w>>1, wc = w&1;
  int g = l>>4, li = l&15;
  int m0 = blockIdx.y*128, n0 = blockIdx.x*128;
  f32x4 acc[4][4] = {};
  for (int kt=0; kt<Dn; kt+=32){
    #pragma unroll
    for (int t=0;t<2;t++){
      int ch = tid + t*256;
      int r = ch>>2, c = (ch&3)*8;
      *(uint4*)&As[r*40+c] = *(const uint4*)&Abf[(size_t)(m0+r)*1024 + kt + c];
      *(uint4*)&Bs[r*40+c] = *(const uint4*)&BT [(size_t)(n0+r)*Dn   + kt + c];
    }
    __syncthreads();
    short8 a[4], b[4];
    #pragma unroll
    for (int i=0;i<4;i++) a[i] = *(const short8*)&As[(wr*64 + i*16 + li)*40 + g*8];
    #pragma unroll
    for (int n=0;n<4;n++) b[n] = *(const short8*)&Bs[(wc*64 + n*16 + li)*40 + g*8];
    #pragma unroll
    for (int i=0;i<4;i++)
      #pragma unroll
      for (int n=0;n<4;n++)
        acc[i][n] = MFMA16(b[n], a[i], acc[i][n]);   // swapped: C[col-group][row]
    __syncthreads();
  }
  #pragma unroll
  for (int i=0;i<4;i++){
    #pragma unroll
    for (int n=0;n<4;n++){
      f32x4 v = acc[i][n];
      float m = fmaxf(fmaxf(v[0],v[1]), fmaxf(v[2],v[3]));
      m = fmaxf(m, __shfl_xor(m,16,64));
      m = fmaxf(m, __shfl_xor(m,32,64));
      if (g==0)
        gmaxT[(size_t)(blockIdx.x*8 + wc*4 + n)*Mn + (m0 + wr*64 + i*16 + li)] = m;
    }
  }
}

// ---------------- 7. per-row top-4 GROUPS from gmaxT ----------------
// block: 64 rows; thread (rl, ch): scans 256 groups for row rl (coalesced over rl).

__global__ __launch_bounds__(256) void gmerge_kernel(const float* __restrict__ gmaxT,
                                                     int* __restrict__ gidx){
  __shared__ u64 part[64][4][4];
  int tid=threadIdx.x;
  int rl = tid&63, ch = tid>>6;
  int row = blockIdx.x*64 + rl;
  u64 k0=0,k1=0,k2=0,k3=0;
  for (int s=0;s<256;s++){
    int gid = ch*256 + s;
    float v = gmaxT[(size_t)gid*Mn + row];
    ins4_64(mkkey(v, gid), k0,k1,k2,k3);
  }
  part[rl][ch][0]=k0; part[rl][ch][1]=k1; part[rl][ch][2]=k2; part[rl][ch][3]=k3;
  __syncthreads();
  if (tid<64){
    u64 a0=part[tid][0][0],a1=part[tid][0][1],a2=part[tid][0][2],a3=part[tid][0][3];
    merge4_64(a0,a1,a2,a3, part[tid][1][0],part[tid][1][1],part[tid][1][2],part[tid][1][3]);
    merge4_64(a0,a1,a2,a3, part[tid][2][0],part[tid][2][1],part[tid][2][2],part[tid][2][3]);
    merge4_64(a0,a1,a2,a3, part[tid][3][0],part[tid][3][1],part[tid][3][2],part[tid][3][3]);
    int r2 = blockIdx.x*64 + tid;
    gidx[(size_t)r2*4+0] = (int)(0xFFFFu - (unsigned)(a0 & 0xFFFFu));
    gidx[(size_t)r2*4+1] = (int)(0xFFFFu - (unsigned)(a1 & 0xFFFFu));
    gidx[(size_t)r2*4+2] = (int)(0xFFFFu - (unsigned)(a2 & 0xFFFFu));
    gidx[(size_t)r2*4+3] = (int)(0xFFFFu - (unsigned)(a3 & 0xFFFFu));
  }
}

// ---------------- 8. exact top-4 recompute over 4 groups x 16 cols ----------------
// wave per row: lane = one of 64 candidate cols; dot(hm_row, BT[col]); u64 wave top-4.

__global__ __launch_bounds__(256) void recompute_kernel(const ushort* __restrict__ cat_bf,
                                                        const ushort* __restrict__ BT,
                                                        const int* __restrict__ gidx,
                                                        int* __restrict__ cand){
  __shared__ float hmf[4][512];
  int tid=threadIdx.x, wid=tid>>6, l=tid&63;
  int row = blockIdx.x*4 + wid;
  {
    uint4 raw = *(const uint4*)&cat_bf[(size_t)row*1024 + l*8];
    const ushort* u = (const ushort*)&raw;
    float4 f0 = make_float4(bf2f(u[0]),bf2f(u[1]),bf2f(u[2]),bf2f(u[3]));
    float4 f1 = make_float4(bf2f(u[4]),bf2f(u[5]),bf2f(u[6]),bf2f(u[7]));
    *(float4*)&hmf[wid][l*8]   = f0;
    *(float4*)&hmf[wid][l*8+4] = f1;
  }
  __syncthreads();
  int gid = gidx[(size_t)row*4 + (l>>4)];
  int col = gid*16 + (l&15);
  const ushort* bp = BT + (size_t)col*Dn;
  float a0=0.f,a1=0.f,a2=0.f,a3=0.f;
  #pragma unroll 8
  for (int j=0;j<64;j++){
    short8 bb = *(const short8*)&bp[j*8];
    float4 h0 = *(const float4*)&hmf[wid][j*8];
    float4 h1 = *(const float4*)&hmf[wid][j*8+4];
    a0 += h0.x*bf2f((ushort)bb[0]) + h1.x*bf2f((ushort)bb[4]);
    a1 += h0.y*bf2f((ushort)bb[1]) + h1.y*bf2f((ushort)bb[5]);
    a2 += h0.z*bf2f((ushort)bb[2]) + h1.z*bf2f((ushort)bb[6]);
    a3 += h0.w*bf2f((ushort)bb[3]) + h1.w*bf2f((ushort)bb[7]);
  }
  float val = (a0+a1)+(a2+a3);
  u64 k0 = mkkey(val, col), k1=0, k2=0, k3=0;
  #pragma unroll
  for (int mask=1; mask<64; mask<<=1){
    u64 b0=__shfl_xor(k0,mask,64), b1=__shfl_xor(k1,mask,64);
    u64 b2=__shfl_xor(k2,mask,64), b3=__shfl_xor(k3,mask,64);
    merge4_64(k0,k1,k2,k3, b0,b1,b2,b3);
  }
  if (l==0){
    cand[(size_t)row*4+0] = (int)(0xFFFFu - (unsigned)(k0 & 0xFFFFu));
    cand[(size_t)row*4+1] = (int)(0xFFFFu - (unsigned)(k1 & 0xFFFFu));
    cand[(size_t)row*4+2] = (int)(0xFFFFu - (unsigned)(k2 & 0xFFFFu));
    cand[(size_t)row*4+3] = (int)(0xFFFFu - (unsigned)(k3 & 0xFFFFu));
  }
}

// ------- 9. gather cand_mem, sim, gumbel select, losses, sel_mem -> cat_bf[:,512:] -------

__global__ __launch_bounds__(256) void select_kernel(const float* __restrict__ hm32,
                                                     const int* __restrict__ cand,
                                                     const int* __restrict__ mem_bank,
                                                     const float* __restrict__ tok_emb,
                                                     const float* __restrict__ gu,
                                                     ushort* __restrict__ cat_bf,
                                                     float* __restrict__ losses){
  __shared__ float cm[4][512];
  __shared__ int ids[32];
  __shared__ float wred[15][4];
  __shared__ int sel_s;
  int row=blockIdx.x, tid=threadIdx.x;
  if (tid<32) ids[tid] = mem_bank[(size_t)cand[(size_t)row*4 + (tid>>3)]*KLn + (tid&7)];
  __syncthreads();
  #pragma unroll
  for (int n=0;n<4;n++){
    float s0=0.f, s1=0.f;
    #pragma unroll
    for (int l=0;l<8;l++){
      const float* e = tok_emb + (size_t)ids[n*8+l]*Dn;
      s0 += e[tid]; s1 += e[tid+256];
    }
    cm[n][tid]=s0*0.125f; cm[n][tid+256]=s1*0.125f;
  }
  __syncthreads();
  float hm0 = hm32[(size_t)row*Dn + tid], hm1 = hm32[(size_t)row*Dn + 256 + tid];
  float c0[4], c1[4];
  #pragma unroll
  for (int n=0;n<4;n++){ c0[n]=cm[n][tid]; c1[n]=cm[n][tid+256]; }
  float p[15];
  p[0]=hm0*hm0+hm1*hm1;
  #pragma unroll
  for (int n=0;n<4;n++) p[1+n]=hm0*c0[n]+hm1*c1[n];
  int qi=5;
  #pragma unroll
  for (int n=0;n<4;n++)
    #pragma unroll
    for (int m=n;m<4;m++) p[qi++]=c0[n]*c0[m]+c1[n]*c1[m];
  int wid=tid>>6, lane=tid&63;
  #pragma unroll
  for (int i=0;i<15;i++) p[i]=wred_sum(p[i]);
  if (lane==0){
    #pragma unroll
    for (int i=0;i<15;i++) wred[i][wid]=p[i];
  }
  __syncthreads();
  if (tid==0){
    float tot[15];
    #pragma unroll
    for (int i=0;i<15;i++) tot[i]=wred[i][0]+wred[i][1]+wred[i][2]+wred[i][3];
    float hn2 = fmaxf(sqrtf(tot[0]), 1e-8f);
    const int diag[4]={5,9,12,14};
    float sim[4], dn[4];
    #pragma unroll
    for (int n=0;n<4;n++){
      float cn = sqrtf(tot[diag[n]]);
      sim[n] = tot[1+n]/(hn2*fmaxf(cn,1e-8f));
      dn[n]  = fmaxf(cn,1e-12f);
    }
    float best=-1e30f; int sel=0;
    #pragma unroll
    for (int n=0;n<4;n++){
      float u = gu[(size_t)row*4+n];
      float g = -logf(-logf(u + 1e-20f) + 1e-20f);
      float a = sim[n]+g;
      if (a>best){ best=a; sel=n; }
    }
    atomicAdd(&losses[0], sim[sel]);
    const int cross[6]={6,7,8,10,11,13};
    const int cn_[6]={0,0,0,1,1,2}, cm_[6]={1,2,3,2,3,3};
    float dv=0.f;
    #pragma unroll
    for (int t=0;t<6;t++) dv += 2.f*tot[cross[t]]/(dn[cn_[t]]*dn[cm_[t]]);
    atomicAdd(&losses[1], dv);
    sel_s=sel;
  }
  __syncthreads();
  int sel=sel_s;
  cat_bf[(size_t)row*1024 + 512 + tid]       = f2bf(cm[sel][tid]);
  cat_bf[(size_t)row*1024 + 512 + 256 + tid] = f2bf(cm[sel][tid+256]);
}

// ---------------- 10. out = h + sigmoid(g+bg)*(m+bm); losses tail ----------------
// gm: [4096][1024] f32, cols 0..511 = gate-linear, 512..1023 = mem-linear.

__global__ __launch_bounds__(256) void final_kernel(const float* __restrict__ h,
                                                    const float* __restrict__ gm,
                                                    const float* __restrict__ bg,
                                                    const float* __restrict__ bm,
                                                    const float* __restrict__ losses,
                                                    float* __restrict__ out){
  int idx = blockIdx.x*256 + threadIdx.x;
  int row = idx >> 9, n = idx & (Dn-1);
  float gl = gm[(size_t)row*1024 + n]       + bg[n];
  float ml = gm[(size_t)row*1024 + 512 + n] + bm[n];
  float gate = 1.f/(1.f+__expf(-gl));
  out[idx] = h[idx] + gate*ml;
  if (idx==0){
    out[(size_t)Mn*Dn]     = -losses[0]*(1.f/(float)Mn);
    out[(size_t)Mn*Dn + 1] =  losses[1]*(1.f/(float)(Mn*NCn*(NCn-1)));
  }
}

// ---------------- launch ----------------

extern "C" void kernel_launch(void* const* d_in, const int* in_sizes, int n_in,
                              void* d_out, int out_size, void* d_ws, size_t ws_size,
                              hipStream_t stream){
  const float* x           = (const float*)d_in[0];
  const float* pos_cos     = (const float*)d_in[1];
  const float* pos_sin     = (const float*)d_in[2];
  const int*   memory_bank = (const int*)  d_in[3];
  const float* tok_emb     = (const float*)d_in[4];
  const float* wq          = (const float*)d_in[5];
  const float* wk          = (const float*)d_in[6];
  const float* wv          = (const float*)d_in[7];
  const float* wo          = (const float*)d_in[8];
  const float* attn_norm_w = (const float*)d_in[9];
  const float* mem_norm_w  = (const float*)d_in[10];
  const float* w_gate      = (const float*)d_in[11];
  const float* wg_fuse     = (const float*)d_in[12];
  const float* bg_fuse     = (const float*)d_in[13];
  const float* wm_fuse     = (const float*)d_in[14];
  const float* bm_fuse     = (const float*)d_in[15];
  const float* gumbel_u    = (const float*)d_in[16];
  float* out = (float*)d_out;

  char* ws = (char*)d_ws;
  const size_t MB = 1u<<20;
  // Lifetime-checked layout:
  //  0-16 : BTg            (convTg -> logits_gmax, recompute)
  // 16-18 : wqkvT+woT      ([wq|wk|wv|wo]^T, 4x512KB contiguous)
  // 18-20 : wgmT           ([wg_fuse|wm_fuse]^T, 2x1MB = [1024][1024])
  // 20-24 : hn_bf -> pv_bf
  // 24-28 : q  28-32: k  32-36: v      (dead after attn)
  // 36-40 : h_attn_bf                  (dead after h_hm)
  // 40-48 : hbuf f32   48-56: hm32 f32   56-64: cat_bf
  // 20-36 : gmaxT 16MB (logits->gmerge)  then gm 16MB (fuse->final)
  // 36MB  : gidx 64KB (gmerge->recompute)  +64KB: cand  +128KB: losses
  ushort* BTg       = (ushort*)(ws);
  ushort* wqkvT     = (ushort*)(ws + 16*MB);
  ushort* woT       = wqkvT + 3*(512*512);
  ushort* wgmT      = (ushort*)(ws + 18*MB);
  ushort* hn_bf     = (ushort*)(ws + 20*MB);
  ushort* pv_bf     = (ushort*)(ws + 20*MB);
  ushort* qkv_bf    = (ushort*)(ws + 24*MB);
  ushort* h_attn_bf = (ushort*)(ws + 36*MB);
  float*  hbuf      = (float*)(ws + 40*MB);
  float*  hm32      = (float*)(ws + 48*MB);
  ushort* cat_bf    = (ushort*)(ws + 56*MB);
  float*  gmaxT     = (float*)(ws + 20*MB);
  float*  gm        = (float*)(ws + 20*MB);
  int*    gidx      = (int*)  (ws + 36*MB);
  int*    cand      = (int*)  (ws + 36*MB + 65536);
  float*  losses    = (float*)(ws + 36*MB + 131072);

  hipMemsetAsync(losses, 0, 2*sizeof(float), stream);

  convT4_kernel<<<dim3(8,8,4),   256, 0, stream>>>(wq, wk, wv, wo, wqkvT);
  convT2_kernel<<<dim3(8,16,2),  256, 0, stream>>>(wg_fuse, wm_fuse, wgmT);
  convT_kernel <<<dim3(256,8),   256, 0, stream>>>(w_gate, BTg, KNn, 512);

  rmsnorm_kernel<<<Mn, 256, 0, stream>>>(x, attn_norm_w, hn_bf);

  // fused QKV: 1536 output cols
  gemm_bf16<4><<<dim3(24, Mn/64), 256, 0, stream>>>(hn_bf, 512, wqkvT, 512,
                                                    qkv_bf, 0, pos_cos, pos_sin);

  ushort* qb_bf = qkv_bf;
  ushort* kb_bf = qkv_bf + (size_t)Mn*Dn;
  ushort* vb_bf = qkv_bf + 2*(size_t)Mn*Dn;
  attn_mfma<<<dim3(Sn/64, Bn*NHn), 256, 0, stream>>>(qb_bf, kb_bf, vb_bf, pv_bf);

  gemm_bf16<3><<<dim3(8, Mn/64), 256, 0, stream>>>(pv_bf, 512, woT, 512,
                                                   h_attn_bf, 512, nullptr, nullptr);

  h_hm_kernel<<<Mn, 256, 0, stream>>>(x, h_attn_bf, mem_norm_w, hbuf, hm32, cat_bf);

  logits_gmax<<<dim3(KNn/128, Mn/128), 256, 0, stream>>>(cat_bf, BTg, gmaxT);
  gmerge_kernel<<<Mn/64, 256, 0, stream>>>(gmaxT, gidx);
  recompute_kernel<<<Mn/4, 256, 0, stream>>>(cat_bf, BTg, gidx, cand);

  select_kernel<<<Mn, 256, 0, stream>>>(hm32, cand, memory_bank, tok_emb, gumbel_u, cat_bf, losses);

  // fused gate+mem linear: 1024 output cols into gm
  gemm_bf16<0><<<dim3(16, Mn/64), 256, 0, stream>>>(cat_bf, 1024, wgmT, 1024,
                                                    gm, 1024, nullptr, nullptr);

  final_kernel<<<(Mn*Dn)/256, 256, 0, stream>>>(hbuf, gm, bg_fuse, bm_fuse, losses, out);
}